// Round 2
// baseline (19177.643 us; speedup 1.0000x reference)
//
#include <hip/hip_runtime.h>

#define T_STEPS 1024
#define BATCH 32
#define HID 512
#define GATES 2048   // 4*HID
#define KDIM 512     // input size == HID

typedef __attribute__((ext_vector_type(8))) short short8;
typedef __attribute__((ext_vector_type(4))) float floatx4;

__device__ __forceinline__ unsigned short f2bf(float f) {
  union { float f; unsigned u; } v; v.f = f;
  return (unsigned short)((v.u + 0x7FFFu + ((v.u >> 16) & 1u)) >> 16);
}
__device__ __forceinline__ float fsigmoid(float x) {
  return 1.0f / (1.0f + __expf(-x));
}
__device__ __forceinline__ float ftanh(float x) {
  return 2.0f / (1.0f + __expf(-2.0f * x)) - 1.0f;
}

// ---------------------------------------------------------------------------
// init: zero h ping-pong buffers + flags (re-run every call; ws is re-poisoned)
// ---------------------------------------------------------------------------
__global__ void init_kernel(unsigned short* __restrict__ hbuf,
                            unsigned* __restrict__ flags) {
  int idx = blockIdx.x * 256 + threadIdx.x;     // 16384 threads
  for (int i = idx; i < 4 * BATCH * HID; i += 64 * 256) hbuf[i] = 0;
  if (idx < 128) flags[idx] = 0u;
}

// ---------------------------------------------------------------------------
// Persistent bidirectional zoneout-LSTM. 64 blocks x 512 thr (regular launch;
// 64 blocks x 8 waves on 256 CUs is trivially co-resident).
// blocks 0..31: forward, 32..63: backward. Block owns 16 hidden units
// (64 gate cols). BOTH W_hh and W_ih fragments live in registers for the
// whole kernel; input projection is computed on the fly per step (it has no
// h-dependence, so it sits before the flag wait).
// One flag-barrier per step per direction; h ping-pong buffer (parity s&1).
// ---------------------------------------------------------------------------
__global__ __launch_bounds__(512) void lstm_persist(
    const float* __restrict__ X,           // [1024, 32, 512]
    const float* __restrict__ Wih,         // [2048, 512]
    const float* __restrict__ Whh,         // [2048, 512]
    const float* __restrict__ bih,         // [2048]
    const float* __restrict__ bhh,         // [2048]
    float* __restrict__ out,               // [1024*32*512] pre-zeroed
    unsigned short* __restrict__ hbuf,     // [2][2][32][512] bf16
    unsigned* __restrict__ flags) {        // [2][64]
  __shared__ unsigned short xs[32][520];   // staged x(t) bf16, +8 pad
  __shared__ unsigned short hs[32][520];   // staged h(s-1) bf16, +8 pad
  __shared__ float gp[2][32][64];          // gate partials per k-half

  const int tid = threadIdx.x;
  const int bid = blockIdx.x;
  const int dir = bid >> 5;
  const int bsl = bid & 31;
  const int u0 = bsl * 16;

  unsigned* myflags = flags + dir * 64;
  unsigned short* hb = hbuf + dir * 2 * (BATCH * HID);

  const int w = tid >> 6, lane = tid & 63;
  const int kh = w >> 2;   // k-half: [kh*256, kh*256+256)
  const int nt = w & 3;    // gate index (16-col n-tile)
  const int colx = lane & 15, q = lane >> 4;

  // Preload this wave's B-fragments into registers: gate nt, unit u0+colx.
  // B[k][n] = W[nt*512 + u0 + colx][k], k = kh*256 + ks*32 + q*8 + j.
  short8 bwh[8], bwx[8];
  {
    const size_t roff = (size_t)(nt * HID + u0 + colx) * KDIM + kh * 256 + q * 8;
    const float* wrh = Whh + roff;
    const float* wrx = Wih + roff;
#pragma unroll
    for (int ks = 0; ks < 8; ++ks) {
      float4 h0 = *(const float4*)(wrh + ks * 32);
      float4 h1 = *(const float4*)(wrh + ks * 32 + 4);
      union { unsigned short u[8]; short8 v; } pk;
      pk.u[0] = f2bf(h0.x); pk.u[1] = f2bf(h0.y); pk.u[2] = f2bf(h0.z); pk.u[3] = f2bf(h0.w);
      pk.u[4] = f2bf(h1.x); pk.u[5] = f2bf(h1.y); pk.u[6] = f2bf(h1.z); pk.u[7] = f2bf(h1.w);
      bwh[ks] = pk.v;
      float4 x0 = *(const float4*)(wrx + ks * 32);
      float4 x1 = *(const float4*)(wrx + ks * 32 + 4);
      union { unsigned short u[8]; short8 v; } px;
      px.u[0] = f2bf(x0.x); px.u[1] = f2bf(x0.y); px.u[2] = f2bf(x0.z); px.u[3] = f2bf(x0.w);
      px.u[4] = f2bf(x1.x); px.u[5] = f2bf(x1.y); px.u[6] = f2bf(x1.z); px.u[7] = f2bf(x1.w);
      bwx[ks] = px.v;
    }
  }

  // Per-thread pointwise assignment: batch b, unit u (global col u0+u)
  const int b = tid >> 4, u = tid & 15;
  const float bias_i = bih[0 * HID + u0 + u] + bhh[0 * HID + u0 + u];
  const float bias_f = bih[1 * HID + u0 + u] + bhh[1 * HID + u0 + u];
  const float bias_g = bih[2 * HID + u0 + u] + bhh[2 * HID + u0 + u];
  const float bias_o = bih[3 * HID + u0 + u] + bhh[3 * HID + u0 + u];

  float c_st = 0.f, h_prev = 0.f;

  for (int s = 0; s < T_STEPS; ++s) {
    const int t = dir ? (T_STEPS - 1 - s) : s;

    // ---- stage x(t) -> LDS bf16 (no h-dependence; overlaps wait in skew) ----
    {
      const float* xt = X + (size_t)t * BATCH * KDIM;
#pragma unroll
      for (int r = 0; r < 8; ++r) {
        int idx = tid + r * 512;          // float4 index 0..4095
        int row = idx >> 7;               // 128 float4 per 512-elem row
        int c4 = (idx & 127) * 4;
        float4 xv = *(const float4*)(xt + (size_t)row * KDIM + c4);
        union { unsigned short u[4]; uint2 v; } p;
        p.u[0] = f2bf(xv.x); p.u[1] = f2bf(xv.y);
        p.u[2] = f2bf(xv.z); p.u[3] = f2bf(xv.w);
        *(uint2*)&xs[row][c4] = p.v;
      }
    }
    __syncthreads();

    // ---- x-projection MFMAs (independent of h) ----
    floatx4 acc0 = {0.f, 0.f, 0.f, 0.f}, acc1 = {0.f, 0.f, 0.f, 0.f};
    {
      const unsigned short* a0p = &xs[colx][kh * 256 + q * 8];
      const unsigned short* a1p = &xs[16 + colx][kh * 256 + q * 8];
#pragma unroll
      for (int ks = 0; ks < 8; ++ks) {
        short8 a0 = *(const short8*)(a0p + ks * 32);
        short8 a1 = *(const short8*)(a1p + ks * 32);
        acc0 = __builtin_amdgcn_mfma_f32_16x16x32_bf16(a0, bwx[ks], acc0, 0, 0, 0);
        acc1 = __builtin_amdgcn_mfma_f32_16x16x32_bf16(a1, bwx[ks], acc1, 0, 0, 0);
      }
    }

    // ---- wait: all blocks of this direction finished step s-1 ----
    if (tid < 64) {
      const unsigned target = (unsigned)s;
      const int fi = tid & 31;
      while (__hip_atomic_load(&myflags[fi], __ATOMIC_RELAXED, __HIP_MEMORY_SCOPE_AGENT) < target)
        __builtin_amdgcn_s_sleep(1);
    }
    __syncthreads();
    __builtin_amdgcn_fence(__ATOMIC_ACQUIRE, "agent");

    // ---- stage h(s-1) -> LDS (32 KB, coalesced uint4) ----
    {
      const uint4* hin = (const uint4*)(hb + (s & 1) * (BATCH * HID));
#pragma unroll
      for (int r = 0; r < 4; ++r) {
        int idx = tid + r * 512;          // uint4 index 0..2047
        int row = idx >> 6;               // 64 uint4 per 512-elem row
        int kc = (idx & 63) * 8;
        *(uint4*)&hs[row][kc] = hin[idx];
      }
    }
    __syncthreads();

    // ---- h-projection MFMAs ----
    {
      const unsigned short* a0p = &hs[colx][kh * 256 + q * 8];
      const unsigned short* a1p = &hs[16 + colx][kh * 256 + q * 8];
#pragma unroll
      for (int ks = 0; ks < 8; ++ks) {
        short8 a0 = *(const short8*)(a0p + ks * 32);
        short8 a1 = *(const short8*)(a1p + ks * 32);
        acc0 = __builtin_amdgcn_mfma_f32_16x16x32_bf16(a0, bwh[ks], acc0, 0, 0, 0);
        acc1 = __builtin_amdgcn_mfma_f32_16x16x32_bf16(a1, bwh[ks], acc1, 0, 0, 0);
      }
    }
#pragma unroll
    for (int r = 0; r < 4; ++r) {
      gp[kh][q * 4 + r][nt * 16 + colx] = acc0[r];
      gp[kh][16 + q * 4 + r][nt * 16 + colx] = acc1[r];
    }
    __syncthreads();

    // ---- pointwise LSTM cell + zoneout for (b, u) ----
    float gi = gp[0][b][u]      + gp[1][b][u]      + bias_i;
    float gf = gp[0][b][16 + u] + gp[1][b][16 + u] + bias_f;
    float gg = gp[0][b][32 + u] + gp[1][b][32 + u] + bias_g;
    float go = gp[0][b][48 + u] + gp[1][b][48 + u] + bias_o;
    float si = fsigmoid(gi);
    float sf = fsigmoid(gf);
    float tg = ftanh(gg);
    float so = fsigmoid(go);
    float c_new = sf * c_st + si * tg;
    float h_new = so * ftanh(c_new);
    c_st = 0.9f * c_new + 0.1f * c_st;
    float h = 0.9f * h_new + 0.1f * h_prev;
    h_prev = h;

    // ---- publish h (bf16) for next step; release flag; then output ----
    unsigned short* hout = hb + ((s + 1) & 1) * (BATCH * HID);
    hout[b * HID + u0 + u] = f2bf(h);
    __threadfence();
    __syncthreads();
    if (tid == 0)
      __hip_atomic_store(&myflags[bsl], (unsigned)(s + 1), __ATOMIC_RELEASE, __HIP_MEMORY_SCOPE_AGENT);

    // off the critical path: accumulate bidirectional output (fwd + bwd)
    atomicAdd(out + (size_t)(t * BATCH + b) * HID + u0 + u, h);
  }
}

// ---------------------------------------------------------------------------
extern "C" void kernel_launch(void* const* d_in, const int* in_sizes, int n_in,
                              void* d_out, int out_size, void* d_ws, size_t ws_size,
                              hipStream_t stream) {
  const float* X   = (const float*)d_in[0];
  const float* Wih = (const float*)d_in[1];
  const float* Whh = (const float*)d_in[2];
  const float* bih = (const float*)d_in[3];
  const float* bhh = (const float*)d_in[4];
  float* out = (float*)d_out;

  // workspace layout: ~132 KB total
  unsigned short* hbuf = (unsigned short*)d_ws;            // [2][2][32][512] bf16
  unsigned* flags = (unsigned*)(hbuf + 4 * BATCH * HID);   // 128 u32

  hipMemsetAsync(d_out, 0, (size_t)out_size * sizeof(float), stream);
  hipLaunchKernelGGL(init_kernel, dim3(64), dim3(256), 0, stream, hbuf, flags);
  hipLaunchKernelGGL(lstm_persist, dim3(64), dim3(512), 0, stream,
                     X, Wih, Whh, bih, bhh, out, hbuf, flags);
}

// Round 3
// 7262.540 us; speedup vs baseline: 2.6406x; 2.6406x over previous
//
#include <hip/hip_runtime.h>

#define T_STEPS 1024
#define BATCH 32
#define HID 512
#define GATES 2048   // 4*HID
#define KDIM 512     // input size == HID

typedef __attribute__((ext_vector_type(8))) short short8;
typedef __attribute__((ext_vector_type(4))) float floatx4;

__device__ __forceinline__ unsigned short f2bf(float f) {
  union { float f; unsigned u; } v; v.f = f;
  return (unsigned short)((v.u + 0x7FFFu + ((v.u >> 16) & 1u)) >> 16);
}
__device__ __forceinline__ float fsigmoid(float x) {
  return 1.0f / (1.0f + __expf(-x));
}
__device__ __forceinline__ float ftanh(float x) {
  return 2.0f / (1.0f + __expf(-2.0f * x)) - 1.0f;
}

// ---------------------------------------------------------------------------
// init: zero h ping-pong buffers + flags with AGENT-scope stores (write-through
// to LLC) so the persistent kernel's sc1 polls/loads never see stale poison.
// ---------------------------------------------------------------------------
__global__ void init_kernel(unsigned* __restrict__ hbuf_u,   // 16384 uints
                            unsigned* __restrict__ flags) {
  int idx = blockIdx.x * 256 + threadIdx.x;     // 16384 threads
  __hip_atomic_store(&hbuf_u[idx], 0u, __ATOMIC_RELAXED, __HIP_MEMORY_SCOPE_AGENT);
  if (idx < 128)
    __hip_atomic_store(&flags[idx], 0u, __ATOMIC_RELAXED, __HIP_MEMORY_SCOPE_AGENT);
}

// ---------------------------------------------------------------------------
// Persistent bidirectional zoneout-LSTM. 64 blocks x 512 thr.
// blocks 0..31: forward, 32..63: backward. Block owns 16 hidden units
// (64 gate cols). W_hh and W_ih fragments live in registers for the whole
// kernel. Cross-block h exchange via LLC using per-access cache-bypass
// (sc0/sc1) atomics — NO agent-scope fences in the loop (those lower to
// full-L2 writeback/invalidate ops and cost ~18 us/step; R2 evidence).
// ---------------------------------------------------------------------------
__global__ __launch_bounds__(512) void lstm_persist(
    const float* __restrict__ X,           // [1024, 32, 512]
    const float* __restrict__ Wih,         // [2048, 512]
    const float* __restrict__ Whh,         // [2048, 512]
    const float* __restrict__ bih,         // [2048]
    const float* __restrict__ bhh,         // [2048]
    float* __restrict__ out,               // [1024*32*512] pre-zeroed
    unsigned short* __restrict__ hbuf,     // [2][2][32][512] bf16
    unsigned* __restrict__ flags) {        // [2][64]
  __shared__ unsigned short xs[32][520];   // staged x(t) bf16, +8 pad
  __shared__ unsigned short hs[32][520];   // staged h(s-1) bf16, +8 pad
  __shared__ float gp[2][32][64];          // gate partials per k-half
  __shared__ unsigned short hsh[32][16];   // h publish staging

  const int tid = threadIdx.x;
  const int bid = blockIdx.x;
  const int dir = bid >> 5;
  const int bsl = bid & 31;
  const int u0 = bsl * 16;

  unsigned* myflags = flags + dir * 64;
  unsigned short* hb = hbuf + dir * 2 * (BATCH * HID);

  const int w = tid >> 6, lane = tid & 63;
  const int kh = w >> 2;   // k-half: [kh*256, kh*256+256)
  const int nt = w & 3;    // gate index (16-col n-tile)
  const int colx = lane & 15, q = lane >> 4;

  // Preload this wave's B-fragments into registers: gate nt, unit u0+colx.
  short8 bwh[8], bwx[8];
  {
    const size_t roff = (size_t)(nt * HID + u0 + colx) * KDIM + kh * 256 + q * 8;
    const float* wrh = Whh + roff;
    const float* wrx = Wih + roff;
#pragma unroll
    for (int ks = 0; ks < 8; ++ks) {
      float4 h0 = *(const float4*)(wrh + ks * 32);
      float4 h1 = *(const float4*)(wrh + ks * 32 + 4);
      union { unsigned short u[8]; short8 v; } pk;
      pk.u[0] = f2bf(h0.x); pk.u[1] = f2bf(h0.y); pk.u[2] = f2bf(h0.z); pk.u[3] = f2bf(h0.w);
      pk.u[4] = f2bf(h1.x); pk.u[5] = f2bf(h1.y); pk.u[6] = f2bf(h1.z); pk.u[7] = f2bf(h1.w);
      bwh[ks] = pk.v;
      float4 x0 = *(const float4*)(wrx + ks * 32);
      float4 x1 = *(const float4*)(wrx + ks * 32 + 4);
      union { unsigned short u[8]; short8 v; } px;
      px.u[0] = f2bf(x0.x); px.u[1] = f2bf(x0.y); px.u[2] = f2bf(x0.z); px.u[3] = f2bf(x0.w);
      px.u[4] = f2bf(x1.x); px.u[5] = f2bf(x1.y); px.u[6] = f2bf(x1.z); px.u[7] = f2bf(x1.w);
      bwx[ks] = px.v;
    }
  }

  // Per-thread pointwise assignment: batch b, unit u (global col u0+u)
  const int b = tid >> 4, u = tid & 15;
  const float bias_i = bih[0 * HID + u0 + u] + bhh[0 * HID + u0 + u];
  const float bias_f = bih[1 * HID + u0 + u] + bhh[1 * HID + u0 + u];
  const float bias_g = bih[2 * HID + u0 + u] + bhh[2 * HID + u0 + u];
  const float bias_o = bih[3 * HID + u0 + u] + bhh[3 * HID + u0 + u];

  float c_st = 0.f, h_prev = 0.f;

  for (int s = 0; s < T_STEPS; ++s) {
    const int t = dir ? (T_STEPS - 1 - s) : s;

    // ---- stage x(t) -> LDS bf16 (plain cached loads; no h-dependence) ----
    {
      const float* xt = X + (size_t)t * BATCH * KDIM;
#pragma unroll
      for (int r = 0; r < 8; ++r) {
        int idx = tid + r * 512;          // float4 index 0..4095
        int row = idx >> 7;               // 128 float4 per 512-elem row
        int c4 = (idx & 127) * 4;
        float4 xv = *(const float4*)(xt + (size_t)row * KDIM + c4);
        union { unsigned short u[4]; uint2 v; } p;
        p.u[0] = f2bf(xv.x); p.u[1] = f2bf(xv.y);
        p.u[2] = f2bf(xv.z); p.u[3] = f2bf(xv.w);
        *(uint2*)&xs[row][c4] = p.v;
      }
    }
    __syncthreads();

    // ---- x-projection MFMAs (independent of h; hides release latency) ----
    floatx4 acc0 = {0.f, 0.f, 0.f, 0.f}, acc1 = {0.f, 0.f, 0.f, 0.f};
    {
      const unsigned short* a0p = &xs[colx][kh * 256 + q * 8];
      const unsigned short* a1p = &xs[16 + colx][kh * 256 + q * 8];
#pragma unroll
      for (int ks = 0; ks < 8; ++ks) {
        short8 a0 = *(const short8*)(a0p + ks * 32);
        short8 a1 = *(const short8*)(a1p + ks * 32);
        acc0 = __builtin_amdgcn_mfma_f32_16x16x32_bf16(a0, bwx[ks], acc0, 0, 0, 0);
        acc1 = __builtin_amdgcn_mfma_f32_16x16x32_bf16(a1, bwx[ks], acc1, 0, 0, 0);
      }
    }

    // ---- wait: all blocks of this direction finished step s-1 ----
    if (tid < 64) {
      const unsigned target = (unsigned)s;
      const int fi = tid & 31;
      while (__hip_atomic_load(&myflags[fi], __ATOMIC_RELAXED, __HIP_MEMORY_SCOPE_AGENT) < target)
        __builtin_amdgcn_s_sleep(1);
    }
    __syncthreads();
    // NO acquire fence: h is loaded below with agent-scope (L2-bypass) atomics.

    // ---- stage h(s-1) -> LDS: per-4B agent loads straight from LLC ----
    {
      const unsigned* hin = (const unsigned*)(hb + (s & 1) * (BATCH * HID));
#pragma unroll
      for (int r = 0; r < 16; ++r) {
        int g = tid + r * 512;            // uint index 0..8191
        unsigned v = __hip_atomic_load(&hin[g], __ATOMIC_RELAXED, __HIP_MEMORY_SCOPE_AGENT);
        int row = g >> 8;                 // 256 uints per 512-halfword row
        int kc = (g & 255) * 2;
        *(unsigned*)&hs[row][kc] = v;
      }
    }
    __syncthreads();

    // ---- h-projection MFMAs ----
    {
      const unsigned short* a0p = &hs[colx][kh * 256 + q * 8];
      const unsigned short* a1p = &hs[16 + colx][kh * 256 + q * 8];
#pragma unroll
      for (int ks = 0; ks < 8; ++ks) {
        short8 a0 = *(const short8*)(a0p + ks * 32);
        short8 a1 = *(const short8*)(a1p + ks * 32);
        acc0 = __builtin_amdgcn_mfma_f32_16x16x32_bf16(a0, bwh[ks], acc0, 0, 0, 0);
        acc1 = __builtin_amdgcn_mfma_f32_16x16x32_bf16(a1, bwh[ks], acc1, 0, 0, 0);
      }
    }
#pragma unroll
    for (int r = 0; r < 4; ++r) {
      gp[kh][q * 4 + r][nt * 16 + colx] = acc0[r];
      gp[kh][16 + q * 4 + r][nt * 16 + colx] = acc1[r];
    }
    __syncthreads();

    // ---- pointwise LSTM cell + zoneout for (b, u) ----
    float gi = gp[0][b][u]      + gp[1][b][u]      + bias_i;
    float gf = gp[0][b][16 + u] + gp[1][b][16 + u] + bias_f;
    float gg = gp[0][b][32 + u] + gp[1][b][32 + u] + bias_g;
    float go = gp[0][b][48 + u] + gp[1][b][48 + u] + bias_o;
    float si = fsigmoid(gi);
    float sf = fsigmoid(gf);
    float tg = ftanh(gg);
    float so = fsigmoid(go);
    float c_new = sf * c_st + si * tg;
    float h_new = so * ftanh(c_new);
    c_st = 0.9f * c_new + 0.1f * c_st;
    float h = 0.9f * h_new + 0.1f * h_prev;
    h_prev = h;

    // ---- publish h: LDS pack, then agent-scope uint stores (write-through) ----
    hsh[b][u] = f2bf(h);
    __syncthreads();
    if (tid < 256) {
      int bb = tid >> 3, j = tid & 3 + 0;       // j in [0,8): recompute below
      j = tid & 7;
      unsigned lo = (unsigned)hsh[bb][2 * j];
      unsigned hi = (unsigned)hsh[bb][2 * j + 1];
      unsigned val = lo | (hi << 16);
      unsigned* hop = (unsigned*)(hb + ((s + 1) & 1) * (BATCH * HID));
      __hip_atomic_store(&hop[(bb * HID + u0) / 2 + j], val,
                         __ATOMIC_RELAXED, __HIP_MEMORY_SCOPE_AGENT);
    }
    __syncthreads();   // drains every thread's vmcnt -> h stores visible at LLC
    if (tid == 0)
      __hip_atomic_store(&myflags[bsl], (unsigned)(s + 1),
                         __ATOMIC_RELEASE, __HIP_MEMORY_SCOPE_AGENT);

    // off the critical path: accumulate bidirectional output (fwd + bwd)
    atomicAdd(out + (size_t)(t * BATCH + b) * HID + u0 + u, h);
  }
}

// ---------------------------------------------------------------------------
extern "C" void kernel_launch(void* const* d_in, const int* in_sizes, int n_in,
                              void* d_out, int out_size, void* d_ws, size_t ws_size,
                              hipStream_t stream) {
  const float* X   = (const float*)d_in[0];
  const float* Wih = (const float*)d_in[1];
  const float* Whh = (const float*)d_in[2];
  const float* bih = (const float*)d_in[3];
  const float* bhh = (const float*)d_in[4];
  float* out = (float*)d_out;

  // workspace layout: ~132 KB total
  unsigned short* hbuf = (unsigned short*)d_ws;            // [2][2][32][512] bf16
  unsigned* flags = (unsigned*)(hbuf + 4 * BATCH * HID);   // 128 u32

  hipMemsetAsync(d_out, 0, (size_t)out_size * sizeof(float), stream);
  hipLaunchKernelGGL(init_kernel, dim3(64), dim3(256), 0, stream,
                     (unsigned*)hbuf, flags);
  hipLaunchKernelGGL(lstm_persist, dim3(64), dim3(512), 0, stream,
                     X, Wih, Whh, bih, bhh, out, hbuf, flags);
}

// Round 4
// 5165.689 us; speedup vs baseline: 3.7125x; 1.4059x over previous
//
#include <hip/hip_runtime.h>

#define T_STEPS 1024
#define BATCH 32
#define HID 512
#define GATES 2048   // 4*HID
#define KDIM 512     // input size == HID

typedef __attribute__((ext_vector_type(8))) short short8;
typedef __attribute__((ext_vector_type(4))) float floatx4;

__device__ __forceinline__ unsigned short f2bf(float f) {
  union { float f; unsigned u; } v; v.f = f;
  return (unsigned short)((v.u + 0x7FFFu + ((v.u >> 16) & 1u)) >> 16);
}
__device__ __forceinline__ float fsigmoid(float x) {
  return 1.0f / (1.0f + __expf(-x));
}
__device__ __forceinline__ float ftanh(float x) {
  return 2.0f / (1.0f + __expf(-2.0f * x)) - 1.0f;
}

// ---------------------------------------------------------------------------
// init: zero h ping-pong buffers + flags with AGENT-scope stores (write-through
// to LLC) so the persistent kernel's sc1 polls/loads never see stale poison.
// ---------------------------------------------------------------------------
__global__ void init_kernel(unsigned* __restrict__ hbuf_u,   // 16384 uints
                            unsigned* __restrict__ flags) {
  int idx = blockIdx.x * 256 + threadIdx.x;     // 16384 threads
  __hip_atomic_store(&hbuf_u[idx], 0u, __ATOMIC_RELAXED, __HIP_MEMORY_SCOPE_AGENT);
  if (idx < 128)
    __hip_atomic_store(&flags[idx], 0u, __ATOMIC_RELAXED, __HIP_MEMORY_SCOPE_AGENT);
}

// ---------------------------------------------------------------------------
// Persistent bidirectional zoneout-LSTM. 64 blocks x 512 thr.
// blocks 0..31: forward, 32..63: backward. Block owns 16 hidden units
// (64 gate cols). W_hh / W_ih fragments live in registers for the whole
// kernel. Cross-block h exchange via LLC with per-access agent-scope
// (sc1) atomics; NO fences and NO release stores anywhere in the loop:
//  - R2 evidence: agent fences lower to full-L2 wb/inv sweeps (~18 us/step).
//  - R3 evidence: agent RELEASE store still sweeps (buffer_wbl2), ~7 us/step.
// Ordering is by construction: h stores are sc1 (coherence point = LLC),
// __syncthreads() drains every thread's vmcnt, THEN the relaxed flag store
// issues — LLC arrival order (h before flag) is guaranteed.
// x(t+1) is prefetched into registers before the poll (hides the per-step
// compulsory L2 miss under the flag wait).
// ---------------------------------------------------------------------------
__global__ __launch_bounds__(512) void lstm_persist(
    const float* __restrict__ X,           // [1024, 32, 512]
    const float* __restrict__ Wih,         // [2048, 512]
    const float* __restrict__ Whh,         // [2048, 512]
    const float* __restrict__ bih,         // [2048]
    const float* __restrict__ bhh,         // [2048]
    float* __restrict__ out,               // [1024*32*512] pre-zeroed
    unsigned short* __restrict__ hbuf,     // [2][2][32][512] bf16
    unsigned* __restrict__ flags) {        // [2][64]
  __shared__ unsigned short xs[32][520];   // staged x(t) bf16, +8 pad
  __shared__ unsigned short hs[32][520];   // staged h(s-1) bf16, +8 pad
  __shared__ float gp[2][32][64];          // gate partials per k-half

  const int tid = threadIdx.x;
  const int bid = blockIdx.x;
  const int dir = bid >> 5;
  const int bsl = bid & 31;
  const int u0 = bsl * 16;

  unsigned* myflags = flags + dir * 64;
  unsigned short* hb = hbuf + dir * 2 * (BATCH * HID);

  const int w = tid >> 6, lane = tid & 63;
  const int kh = w >> 2;   // k-half: [kh*256, kh*256+256)
  const int nt = w & 3;    // gate index (16-col n-tile)
  const int colx = lane & 15, q = lane >> 4;

  // Preload this wave's B-fragments into registers: gate nt, unit u0+colx.
  short8 bwh[8], bwx[8];
  {
    const size_t roff = (size_t)(nt * HID + u0 + colx) * KDIM + kh * 256 + q * 8;
    const float* wrh = Whh + roff;
    const float* wrx = Wih + roff;
#pragma unroll
    for (int ks = 0; ks < 8; ++ks) {
      float4 h0 = *(const float4*)(wrh + ks * 32);
      float4 h1 = *(const float4*)(wrh + ks * 32 + 4);
      union { unsigned short u[8]; short8 v; } pk;
      pk.u[0] = f2bf(h0.x); pk.u[1] = f2bf(h0.y); pk.u[2] = f2bf(h0.z); pk.u[3] = f2bf(h0.w);
      pk.u[4] = f2bf(h1.x); pk.u[5] = f2bf(h1.y); pk.u[6] = f2bf(h1.z); pk.u[7] = f2bf(h1.w);
      bwh[ks] = pk.v;
      float4 x0 = *(const float4*)(wrx + ks * 32);
      float4 x1 = *(const float4*)(wrx + ks * 32 + 4);
      union { unsigned short u[8]; short8 v; } px;
      px.u[0] = f2bf(x0.x); px.u[1] = f2bf(x0.y); px.u[2] = f2bf(x0.z); px.u[3] = f2bf(x0.w);
      px.u[4] = f2bf(x1.x); px.u[5] = f2bf(x1.y); px.u[6] = f2bf(x1.z); px.u[7] = f2bf(x1.w);
      bwx[ks] = px.v;
    }
  }

  // Per-thread pointwise assignment: batch b, unit u (global col u0+u)
  const int b = tid >> 4, u = tid & 15;
  const float bias_i = bih[0 * HID + u0 + u] + bhh[0 * HID + u0 + u];
  const float bias_f = bih[1 * HID + u0 + u] + bhh[1 * HID + u0 + u];
  const float bias_g = bih[2 * HID + u0 + u] + bhh[2 * HID + u0 + u];
  const float bias_o = bih[3 * HID + u0 + u] + bhh[3 * HID + u0 + u];

  float c_st = 0.f, h_prev = 0.f;

  // ---- prologue: prefetch x(t0) into registers ----
  float4 xr[8];
  {
    const int t0 = dir ? (T_STEPS - 1) : 0;
    const float* xt = X + (size_t)t0 * BATCH * KDIM;
#pragma unroll
    for (int r = 0; r < 8; ++r) {
      int idx = tid + r * 512;
      xr[r] = *(const float4*)(xt + (size_t)(idx >> 7) * KDIM + (idx & 127) * 4);
    }
  }

  for (int s = 0; s < T_STEPS; ++s) {
    const int t = dir ? (T_STEPS - 1 - s) : s;

    // ---- convert prefetched x(t) -> LDS bf16 ----
#pragma unroll
    for (int r = 0; r < 8; ++r) {
      int idx = tid + r * 512;
      int row = idx >> 7;
      int c4 = (idx & 127) * 4;
      union { unsigned short u[4]; uint2 v; } p;
      p.u[0] = f2bf(xr[r].x); p.u[1] = f2bf(xr[r].y);
      p.u[2] = f2bf(xr[r].z); p.u[3] = f2bf(xr[r].w);
      *(uint2*)&xs[row][c4] = p.v;
    }
    __syncthreads();

    // ---- x-projection MFMAs (independent of h) ----
    floatx4 acc0 = {0.f, 0.f, 0.f, 0.f}, acc1 = {0.f, 0.f, 0.f, 0.f};
    {
      const unsigned short* a0p = &xs[colx][kh * 256 + q * 8];
      const unsigned short* a1p = &xs[16 + colx][kh * 256 + q * 8];
#pragma unroll
      for (int ks = 0; ks < 8; ++ks) {
        short8 a0 = *(const short8*)(a0p + ks * 32);
        short8 a1 = *(const short8*)(a1p + ks * 32);
        acc0 = __builtin_amdgcn_mfma_f32_16x16x32_bf16(a0, bwx[ks], acc0, 0, 0, 0);
        acc1 = __builtin_amdgcn_mfma_f32_16x16x32_bf16(a1, bwx[ks], acc1, 0, 0, 0);
      }
    }

    // ---- issue x(t+1) prefetch; completes during the flag wait ----
    {
      const int sn = (s + 1 < T_STEPS) ? (s + 1) : s;
      const int tn = dir ? (T_STEPS - 1 - sn) : sn;
      const float* xt = X + (size_t)tn * BATCH * KDIM;
#pragma unroll
      for (int r = 0; r < 8; ++r) {
        int idx = tid + r * 512;
        xr[r] = *(const float4*)(xt + (size_t)(idx >> 7) * KDIM + (idx & 127) * 4);
      }
    }

    // ---- wait: all blocks of this direction finished step s-1 ----
    if (tid < 32) {
      const unsigned target = (unsigned)s;
      while (__hip_atomic_load(&myflags[tid], __ATOMIC_RELAXED, __HIP_MEMORY_SCOPE_AGENT) < target)
        __builtin_amdgcn_s_sleep(1);
    }
    __syncthreads();

    // ---- stage h(s-1) -> LDS: 8B agent-scope loads straight from LLC ----
    {
      const unsigned long long* hin =
          (const unsigned long long*)(hb + (s & 1) * (BATCH * HID));
#pragma unroll
      for (int r = 0; r < 8; ++r) {
        int g = tid + r * 512;            // qword index 0..4095
        unsigned long long v =
            __hip_atomic_load(&hin[g], __ATOMIC_RELAXED, __HIP_MEMORY_SCOPE_AGENT);
        int row = g >> 7;                 // 128 qwords per 512-halfword row
        int kc = (g & 127) * 4;
        *(unsigned long long*)&hs[row][kc] = v;
      }
    }
    __syncthreads();

    // ---- h-projection MFMAs ----
    {
      const unsigned short* a0p = &hs[colx][kh * 256 + q * 8];
      const unsigned short* a1p = &hs[16 + colx][kh * 256 + q * 8];
#pragma unroll
      for (int ks = 0; ks < 8; ++ks) {
        short8 a0 = *(const short8*)(a0p + ks * 32);
        short8 a1 = *(const short8*)(a1p + ks * 32);
        acc0 = __builtin_amdgcn_mfma_f32_16x16x32_bf16(a0, bwh[ks], acc0, 0, 0, 0);
        acc1 = __builtin_amdgcn_mfma_f32_16x16x32_bf16(a1, bwh[ks], acc1, 0, 0, 0);
      }
    }
#pragma unroll
    for (int r = 0; r < 4; ++r) {
      gp[kh][q * 4 + r][nt * 16 + colx] = acc0[r];
      gp[kh][16 + q * 4 + r][nt * 16 + colx] = acc1[r];
    }
    __syncthreads();

    // ---- pointwise LSTM cell + zoneout for (b, u) ----
    float gi = gp[0][b][u]      + gp[1][b][u]      + bias_i;
    float gf = gp[0][b][16 + u] + gp[1][b][16 + u] + bias_f;
    float gg = gp[0][b][32 + u] + gp[1][b][32 + u] + bias_g;
    float go = gp[0][b][48 + u] + gp[1][b][48 + u] + bias_o;
    float si = fsigmoid(gi);
    float sf = fsigmoid(gf);
    float tg = ftanh(gg);
    float so = fsigmoid(go);
    float c_new = sf * c_st + si * tg;
    float h_new = so * ftanh(c_new);
    c_st = 0.9f * c_new + 0.1f * c_st;
    float h = 0.9f * h_new + 0.1f * h_prev;
    h_prev = h;

    // ---- publish h: shfl pair-pack, agent-scope uint stores (no LDS hop) ----
    {
      float hp = __shfl_xor(h, 1);
      if (!(tid & 1)) {
        unsigned val = (unsigned)f2bf(h) | ((unsigned)f2bf(hp) << 16);
        unsigned* hop = (unsigned*)(hb + ((s + 1) & 1) * (BATCH * HID));
        __hip_atomic_store(&hop[(b * HID + u0 + u) >> 1], val,
                           __ATOMIC_RELAXED, __HIP_MEMORY_SCOPE_AGENT);
      }
    }
    __syncthreads();   // drains every thread's vmcnt -> h stores at LLC
    if (tid == 0)      // RELAXED: no wbl2 sweep; order by construction (above)
      __hip_atomic_store(&myflags[bsl], (unsigned)(s + 1),
                         __ATOMIC_RELAXED, __HIP_MEMORY_SCOPE_AGENT);

    // off the critical path: accumulate bidirectional output (fwd + bwd)
    atomicAdd(out + (size_t)(t * BATCH + b) * HID + u0 + u, h);
  }
}

// ---------------------------------------------------------------------------
extern "C" void kernel_launch(void* const* d_in, const int* in_sizes, int n_in,
                              void* d_out, int out_size, void* d_ws, size_t ws_size,
                              hipStream_t stream) {
  const float* X   = (const float*)d_in[0];
  const float* Wih = (const float*)d_in[1];
  const float* Whh = (const float*)d_in[2];
  const float* bih = (const float*)d_in[3];
  const float* bhh = (const float*)d_in[4];
  float* out = (float*)d_out;

  // workspace layout: ~132 KB total
  unsigned short* hbuf = (unsigned short*)d_ws;            // [2][2][32][512] bf16
  unsigned* flags = (unsigned*)(hbuf + 4 * BATCH * HID);   // 128 u32

  hipMemsetAsync(d_out, 0, (size_t)out_size * sizeof(float), stream);
  hipLaunchKernelGGL(init_kernel, dim3(64), dim3(256), 0, stream,
                     (unsigned*)hbuf, flags);
  hipLaunchKernelGGL(lstm_persist, dim3(64), dim3(512), 0, stream,
                     X, Wih, Whh, bih, bhh, out, hbuf, flags);
}